// Round 1
// baseline (1266.792 us; speedup 1.0000x reference)
//
#include <hip/hip_runtime.h>
#include <cstdint>
#include <cstddef>

typedef unsigned short u16;
typedef __bf16 bf16x8 __attribute__((ext_vector_type(8)));
typedef u16    u16x8  __attribute__((ext_vector_type(8)));
typedef float  f32x4  __attribute__((ext_vector_type(4)));

#define NW 840
#define NTOK 144
#define DIM 192
#define HEADS 6
#define TABLE_ROWS 3312
#define SCALE 0.17677669529663687f

// fp32 -> bf16 bits, round-to-nearest-even (inputs finite)
__device__ __forceinline__ u16 f2b_bits(float f) {
  unsigned u = __builtin_bit_cast(unsigned, f);
  return (u16)((u + 0x7FFFu + ((u >> 16) & 1u)) >> 16);
}

__device__ __forceinline__ bf16x8 ld_bf8(const u16* p) {
  return __builtin_bit_cast(bf16x8, *(const u16x8*)p);
}

__device__ __forceinline__ f32x4 mfma16(bf16x8 a, bf16x8 b, f32x4 c) {
  return __builtin_amdgcn_mfma_f32_16x16x32_bf16(a, b, c, 0, 0, 0);
}

// ---------------------------------------------------------------------------
// K0: bias_table (3312,840,6) -> bias_t[w][h][p]  +  w1,w2 -> bf16
// grid: 52*79 transpose blocks + 576 convert blocks, 256 threads
// ---------------------------------------------------------------------------
__global__ void k_prep(const float* __restrict__ bt, const float* __restrict__ w1,
                       const float* __restrict__ w2, float* __restrict__ bto,
                       u16* __restrict__ w1b, u16* __restrict__ w2b) {
  __shared__ float tile[64 * 65];
  int bid = blockIdx.x, tid = threadIdx.x;
  if (bid < 52 * 79) {
    int p0 = (bid % 52) * 64;
    int wh0 = (bid / 52) * 64;
    #pragma unroll
    for (int it = 0; it < 16; ++it) {
      int idx = tid + it * 256;
      int pp = idx >> 6, cc = idx & 63;
      float v = 0.f;
      if (p0 + pp < TABLE_ROWS && wh0 + cc < NW * HEADS)
        v = bt[(size_t)(p0 + pp) * (NW * HEADS) + wh0 + cc];
      tile[pp * 65 + cc] = v;
    }
    __syncthreads();
    #pragma unroll
    for (int it = 0; it < 16; ++it) {
      int idx = tid + it * 256;
      int rr = idx >> 6, cc2 = idx & 63;
      if (wh0 + rr < NW * HEADS && p0 + cc2 < TABLE_ROWS)
        bto[(size_t)(wh0 + rr) * TABLE_ROWS + p0 + cc2] = tile[cc2 * 65 + rr];
    }
  } else {
    int i = (bid - 52 * 79) * 256 + tid;
    if (i < 576 * DIM) {
      w1b[i] = f2b_bits(w1[i]);
    } else {
      int j = i - 576 * DIM;
      if (j < DIM * DIM) w2b[j] = f2b_bits(w2[j]);
    }
  }
}

// ---------------------------------------------------------------------------
// K1: fused QKV + attention per (b,w) block; 576 threads = 9 waves.
//   wave w: phase1 part p=w/3 (0=Q,1=K,2=V), M-tiles {w%3, w%3+3, w%3+6}
//           phase2/3 row-tile r = w (rows 16r..16r+16)
//   O (bf16) -> ws
// ---------------------------------------------------------------------------
__global__ __launch_bounds__(576) void k_attn(
    const float* __restrict__ x, const float* __restrict__ mask,
    const float* __restrict__ b1, const u16* __restrict__ w1b,
    const float* __restrict__ bias_t, const int* __restrict__ pos,
    u16* __restrict__ Ow) {
  // LDS: strides padded so 16-lane frag reads hit >=8 distinct bank groups (2-way = free)
  __shared__ __align__(16) u16 q_lds[NTOK * 40];   // [n][d], stride 40
  __shared__ __align__(16) u16 k_lds[NTOK * 40];   // [m][d], stride 40
  __shared__ __align__(16) u16 vt[32 * 168];       // [dd][m], stride 168, cols 144..159 zero pad
  __shared__ __align__(16) u16 pch[NTOK * 40];     // per-wave P chunk [n][mm], stride 40
  __shared__ float bias_s[TABLE_ROWS];             // bias_t slice for current (w,h)

  const int tid = threadIdx.x;
  const int w = tid >> 6;
  const int l = tid & 63;
  const int c = l & 15;        // lane&15
  const int q4 = l >> 4;       // quad
  const int bw = blockIdx.x;
  const int b = bw / NW;
  const int ww = bw % NW;

  const float* xg = x + (size_t)bw * (NTOK * DIM);

  // zero Vt pad columns m in [144,160) once per block
  if (tid < 512) vt[(tid >> 4) * 168 + 144 + (tid & 15)] = 0;

  // ---- x A-frags in registers: 3 M-tiles x 6 k-steps, reused for all heads
  const int m3 = w % 3;
  const int p = w / 3;  // 0=Q,1=K,2=V
  const int r = w;      // phase2/3 row tile
  bf16x8 xf[3][6];
  #pragma unroll
  for (int i = 0; i < 3; ++i) {
    const int mti = m3 + 3 * i;
    const float* rp = xg + (size_t)(mti * 16 + c) * DIM;
    #pragma unroll
    for (int ks = 0; ks < 6; ++ks) {
      const float4* fp = (const float4*)(rp + ks * 32 + q4 * 8);
      float4 f0 = fp[0], f1 = fp[1];
      u16x8 rr;
      rr[0] = f2b_bits(f0.x); rr[1] = f2b_bits(f0.y);
      rr[2] = f2b_bits(f0.z); rr[3] = f2b_bits(f0.w);
      rr[4] = f2b_bits(f1.x); rr[5] = f2b_bits(f1.y);
      rr[6] = f2b_bits(f1.z); rr[7] = f2b_bits(f1.w);
      xf[i][ks] = __builtin_bit_cast(bf16x8, rr);
    }
  }

  const f32x4 z = {0.f, 0.f, 0.f, 0.f};
  const int n0 = r * 16 + q4 * 4;
  const int* pr[4];
  const float* mr[4];
  #pragma unroll
  for (int g = 0; g < 4; ++g) {
    pr[g] = pos + (n0 + g) * NTOK;
    mr[g] = mask + (size_t)b * (NTOK * NTOK) + (size_t)(n0 + g) * NTOK;
  }

  for (int h = 0; h < HEADS; ++h) {
    // ---- phase 1: QKV slice GEMM (this wave: part p, 3 M-tiles, 2 N-tiles)
    f32x4 acc[3][2];
    #pragma unroll
    for (int i = 0; i < 3; ++i) { acc[i][0] = z; acc[i][1] = z; }
    const int obase = p * DIM + h * 32;
    #pragma unroll
    for (int ks = 0; ks < 6; ++ks) {
      bf16x8 w0 = ld_bf8(w1b + (size_t)(obase + c) * DIM + ks * 32 + q4 * 8);
      bf16x8 w1f = ld_bf8(w1b + (size_t)(obase + 16 + c) * DIM + ks * 32 + q4 * 8);
      #pragma unroll
      for (int i = 0; i < 3; ++i) {
        acc[i][0] = mfma16(xf[i][ks], w0, acc[i][0]);
        acc[i][1] = mfma16(xf[i][ks], w1f, acc[i][1]);
      }
    }
    float b1v[2] = {b1[obase + c], b1[obase + 16 + c]};

    // ---- epilogue: write Q/K ([n][d]) or V^T ([dd][m]) to LDS
    if (p < 2) {
      u16* dst = (p == 0) ? q_lds : k_lds;
      #pragma unroll
      for (int i = 0; i < 3; ++i) {
        const int rowb = (m3 + 3 * i) * 16 + q4 * 4;
        #pragma unroll
        for (int j = 0; j < 2; ++j)
          #pragma unroll
          for (int reg = 0; reg < 4; ++reg)
            dst[(rowb + reg) * 40 + j * 16 + c] = f2b_bits(acc[i][j][reg] + b1v[j]);
      }
    } else {
      #pragma unroll
      for (int i = 0; i < 3; ++i) {
        const int mb = (m3 + 3 * i) * 16 + q4 * 4;
        #pragma unroll
        for (int j = 0; j < 2; ++j) {
          unsigned lo = (unsigned)f2b_bits(acc[i][j][0] + b1v[j]) |
                        ((unsigned)f2b_bits(acc[i][j][1] + b1v[j]) << 16);
          unsigned hi = (unsigned)f2b_bits(acc[i][j][2] + b1v[j]) |
                        ((unsigned)f2b_bits(acc[i][j][3] + b1v[j]) << 16);
          uint2 u; u.x = lo; u.y = hi;
          *(uint2*)&vt[(j * 16 + c) * 168 + mb] = u;
        }
      }
    }

    // ---- stage bias_t slice for (ww, h) into LDS
    {
      const float* src = bias_t + (size_t)(ww * HEADS + h) * TABLE_ROWS;
      for (int idx = tid; idx < TABLE_ROWS; idx += 576) bias_s[idx] = src[idx];
    }
    __syncthreads();

    // ---- phase 2: S = (Q.K^T)*scale + bias + mask, softmax (rows of tile r)
    bf16x8 qa = ld_bf8(&q_lds[(r * 16 + c) * 40 + q4 * 8]);
    f32x4 S[9];
    #pragma unroll
    for (int ct = 0; ct < 9; ++ct)
      S[ct] = mfma16(qa, ld_bf8(&k_lds[(ct * 16 + c) * 40 + q4 * 8]), z);

    #pragma unroll
    for (int ct = 0; ct < 9; ++ct) {
      const int m = ct * 16 + c;
      #pragma unroll
      for (int g = 0; g < 4; ++g)
        S[ct][g] = S[ct][g] * SCALE + bias_s[pr[g][m]] + mr[g][m];
    }
    float mx[4] = {-3e38f, -3e38f, -3e38f, -3e38f};
    #pragma unroll
    for (int ct = 0; ct < 9; ++ct)
      #pragma unroll
      for (int g = 0; g < 4; ++g) mx[g] = fmaxf(mx[g], S[ct][g]);
    #pragma unroll
    for (int g = 0; g < 4; ++g) {
      mx[g] = fmaxf(mx[g], __shfl_xor(mx[g], 1));
      mx[g] = fmaxf(mx[g], __shfl_xor(mx[g], 2));
      mx[g] = fmaxf(mx[g], __shfl_xor(mx[g], 4));
      mx[g] = fmaxf(mx[g], __shfl_xor(mx[g], 8));
    }
    float sm[4] = {0.f, 0.f, 0.f, 0.f};
    #pragma unroll
    for (int ct = 0; ct < 9; ++ct)
      #pragma unroll
      for (int g = 0; g < 4; ++g) {
        float e = __expf(S[ct][g] - mx[g]);
        S[ct][g] = e;
        sm[g] += e;
      }
    #pragma unroll
    for (int g = 0; g < 4; ++g) {
      sm[g] += __shfl_xor(sm[g], 1);
      sm[g] += __shfl_xor(sm[g], 2);
      sm[g] += __shfl_xor(sm[g], 4);
      sm[g] += __shfl_xor(sm[g], 8);
    }
    float inv[4];
    #pragma unroll
    for (int g = 0; g < 4; ++g) inv[g] = 1.0f / sm[g];

    // ---- phase 3: O = P.V via per-wave P chunks (no barriers; same-wave LDS in order)
    f32x4 oacc[2] = {z, z};
    #pragma unroll
    for (int ks = 0; ks < 5; ++ks) {
      #pragma unroll
      for (int cti = 0; cti < 2; ++cti) {
        const int ct = 2 * ks + cti;
        #pragma unroll
        for (int g = 0; g < 4; ++g) {
          u16 pv = 0;
          if (ct < 9) pv = f2b_bits(S[ct][g] * inv[g]);
          pch[(r * 16 + q4 * 4 + g) * 40 + cti * 16 + c] = pv;
        }
      }
      __asm__ volatile("" ::: "memory");  // keep program order write->read
      bf16x8 pa = ld_bf8(&pch[(r * 16 + c) * 40 + q4 * 8]);
      oacc[0] = mfma16(pa, ld_bf8(&vt[(c) * 168 + ks * 32 + q4 * 8]), oacc[0]);
      oacc[1] = mfma16(pa, ld_bf8(&vt[(16 + c) * 168 + ks * 32 + q4 * 8]), oacc[1]);
      __asm__ volatile("" ::: "memory");  // don't sink reads below next iter's writes
    }

    // ---- store O (bf16) to ws: [bw*144+n][h*32+dd]
    #pragma unroll
    for (int j = 0; j < 2; ++j)
      #pragma unroll
      for (int g = 0; g < 4; ++g)
        Ow[((size_t)bw * NTOK + r * 16 + q4 * 4 + g) * DIM + h * 32 + j * 16 + c] =
            f2b_bits(oacc[j][g]);

    __syncthreads();  // protect Q/K/Vt/bias_s before next head overwrites
  }
}

// ---------------------------------------------------------------------------
// K2: out = O @ w2^T + b2 ; LDS-free, per-(b,w) block, 576 threads = 9 waves
//   wave: M-tiles {w%3, w%3+3, w%3+6}, N-tiles [4*(w/3) .. +4)
// ---------------------------------------------------------------------------
__global__ __launch_bounds__(576) void k_proj(const u16* __restrict__ Ow,
                                              const u16* __restrict__ w2b,
                                              const float* __restrict__ b2,
                                              float* __restrict__ out) {
  const int tid = threadIdx.x;
  const int w = tid >> 6;
  const int l = tid & 63;
  const int c = l & 15, q4 = l >> 4;
  const int bw = blockIdx.x;
  const int m3 = w % 3, ntg = w / 3;
  const size_t rbase = (size_t)bw * NTOK;

  const f32x4 z = {0.f, 0.f, 0.f, 0.f};
  f32x4 acc[3][4];
  #pragma unroll
  for (int i = 0; i < 3; ++i)
    #pragma unroll
    for (int j = 0; j < 4; ++j) acc[i][j] = z;

  #pragma unroll
  for (int ks = 0; ks < 6; ++ks) {
    bf16x8 af[3];
    #pragma unroll
    for (int i = 0; i < 3; ++i)
      af[i] = ld_bf8(Ow + (rbase + (m3 + 3 * i) * 16 + c) * DIM + ks * 32 + q4 * 8);
    bf16x8 bfg[4];
    #pragma unroll
    for (int j = 0; j < 4; ++j)
      bfg[j] = ld_bf8(w2b + (size_t)(ntg * 64 + j * 16 + c) * DIM + ks * 32 + q4 * 8);
    #pragma unroll
    for (int i = 0; i < 3; ++i)
      #pragma unroll
      for (int j = 0; j < 4; ++j) acc[i][j] = mfma16(af[i], bfg[j], acc[i][j]);
  }

  float b2v[4];
  #pragma unroll
  for (int j = 0; j < 4; ++j) b2v[j] = b2[ntg * 64 + j * 16 + c];

  #pragma unroll
  for (int i = 0; i < 3; ++i) {
    const int rowb = (m3 + 3 * i) * 16 + q4 * 4;
    #pragma unroll
    for (int j = 0; j < 4; ++j)
      #pragma unroll
      for (int g = 0; g < 4; ++g)
        out[(rbase + rowb + g) * DIM + ntg * 64 + j * 16 + c] = acc[i][j][g] + b2v[j];
  }
}

// ---------------------------------------------------------------------------
extern "C" void kernel_launch(void* const* d_in, const int* in_sizes, int n_in,
                              void* d_out, int out_size, void* d_ws, size_t ws_size,
                              hipStream_t stream) {
  const float* x = (const float*)d_in[0];
  const float* mask = (const float*)d_in[1];
  const float* w1 = (const float*)d_in[2];
  const float* b1 = (const float*)d_in[3];
  const float* w2 = (const float*)d_in[4];
  const float* b2 = (const float*)d_in[5];
  const float* bias_table = (const float*)d_in[6];
  const int* pos = (const int*)d_in[7];
  float* out = (float*)d_out;

  char* ws = (char*)d_ws;
  // ws layout (bytes):
  //   bias_t : 3312*840*6*4       = 66,769,920
  //   w1b    : 576*192*2          =    221,184   @ 66,769,920
  //   w2b    : 192*192*2          =     73,728   @ 66,991,104
  //   Ow     : 2*840*144*192*2    = 92,897,280   @ 67,064,832  (total ~160 MB)
  float* bias_t = (float*)ws;
  u16* w1b = (u16*)(ws + 66769920);
  u16* w2b = (u16*)(ws + 66991104);
  u16* Ow = (u16*)(ws + 67064832);

  k_prep<<<dim3(52 * 79 + 576), dim3(256), 0, stream>>>(bias_table, w1, w2,
                                                        bias_t, w1b, w2b);
  k_attn<<<dim3(2 * NW), dim3(576), 0, stream>>>(x, mask, b1, w1b, bias_t, pos, Ow);
  k_proj<<<dim3(2 * NW), dim3(576), 0, stream>>>(Ow, w2b, b2, out);
}

// Round 2
// 1035.300 us; speedup vs baseline: 1.2236x; 1.2236x over previous
//
#include <hip/hip_runtime.h>
#include <cstdint>
#include <cstddef>

typedef unsigned short u16;
typedef __bf16 bf16x8 __attribute__((ext_vector_type(8)));
typedef u16    u16x8  __attribute__((ext_vector_type(8)));
typedef float  f32x4  __attribute__((ext_vector_type(4)));

#define NW 840
#define NTOK 144
#define DIM 192
#define HEADS 6
#define TABLE_ROWS 3312
#define SCALE 0.17677669529663687f

// fp32 -> bf16 bits, round-to-nearest-even (inputs finite)
__device__ __forceinline__ u16 f2b_bits(float f) {
  unsigned u = __builtin_bit_cast(unsigned, f);
  return (u16)((u + 0x7FFFu + ((u >> 16) & 1u)) >> 16);
}

__device__ __forceinline__ bf16x8 ld_bf8(const u16* p) {
  return __builtin_bit_cast(bf16x8, *(const u16x8*)p);
}

__device__ __forceinline__ f32x4 mfma16(bf16x8 a, bf16x8 b, f32x4 c) {
  return __builtin_amdgcn_mfma_f32_16x16x32_bf16(a, b, c, 0, 0, 0);
}

// ---------------------------------------------------------------------------
// K0: bias_table (3312,840,6) -> bias_t[w][h][p]  +  w1,w2 -> bf16
// ---------------------------------------------------------------------------
__global__ void k_prep(const float* __restrict__ bt, const float* __restrict__ w1,
                       const float* __restrict__ w2, float* __restrict__ bto,
                       u16* __restrict__ w1b, u16* __restrict__ w2b) {
  __shared__ float tile[64 * 65];
  int bid = blockIdx.x, tid = threadIdx.x;
  if (bid < 52 * 79) {
    int p0 = (bid % 52) * 64;
    int wh0 = (bid / 52) * 64;
    #pragma unroll
    for (int it = 0; it < 16; ++it) {
      int idx = tid + it * 256;
      int pp = idx >> 6, cc = idx & 63;
      float v = 0.f;
      if (p0 + pp < TABLE_ROWS && wh0 + cc < NW * HEADS)
        v = bt[(size_t)(p0 + pp) * (NW * HEADS) + wh0 + cc];
      tile[pp * 65 + cc] = v;
    }
    __syncthreads();
    #pragma unroll
    for (int it = 0; it < 16; ++it) {
      int idx = tid + it * 256;
      int rr = idx >> 6, cc2 = idx & 63;
      if (wh0 + rr < NW * HEADS && p0 + cc2 < TABLE_ROWS)
        bto[(size_t)(wh0 + rr) * TABLE_ROWS + p0 + cc2] = tile[cc2 * 65 + rr];
    }
  } else {
    int i = (bid - 52 * 79) * 256 + tid;
    if (i < 576 * DIM) {
      w1b[i] = f2b_bits(w1[i]);
    } else {
      int j = i - 576 * DIM;
      if (j < DIM * DIM) w2b[j] = f2b_bits(w2[j]);
    }
  }
}

// ---------------------------------------------------------------------------
// K1: one block per (b, window, head); 192 threads = 3 waves.
//   Wave w: QKV GEMM for M-tiles {w, w+3, w+6} (head slice only),
//           then attention rows of the same tiles.
//   LDS 34.5 KB -> 4 blocks/CU (12 waves), vs 58.9 KB / 1 block before.
// ---------------------------------------------------------------------------
__global__ __launch_bounds__(192, 3) void k_attn(
    const float* __restrict__ x, const float* __restrict__ mask,
    const float* __restrict__ b1, const u16* __restrict__ w1b,
    const float* __restrict__ bias_t, const int* __restrict__ pos,
    u16* __restrict__ Ow) {
  __shared__ __align__(16) u16 q_lds[NTOK * 36];   // [n][d], stride 36 (conflict-free reads)
  __shared__ __align__(16) u16 k_lds[NTOK * 36];   // [m][d], stride 36
  __shared__ __align__(16) u16 vt[32 * 168];       // [dd][m], stride 168, cols 144..159 zero
  __shared__ __align__(16) u16 pch[3 * 16 * 40];   // per-wave P chunk [16][40]

  const int tid = threadIdx.x;
  const int w = tid >> 6;       // wave 0..2
  const int l = tid & 63;
  const int c = l & 15;
  const int q4 = l >> 4;
  const int bid = blockIdx.x;
  const int h = bid % HEADS;
  const int bw = bid / HEADS;   // 0..1679
  const int b = bw / NW;
  const int ww = bw % NW;

  const float* xg = x + (size_t)bw * (NTOK * DIM);
  const float* bias_g = bias_t + (size_t)(ww * HEADS + h) * TABLE_ROWS;
  const float* mask_g = mask + (size_t)b * (NTOK * NTOK);

  // zero vt pad columns m in [144,160)
  for (int i = tid; i < 512; i += 192) vt[(i >> 4) * 168 + 144 + (i & 15)] = 0;

  // hoisted b1 values for this head's 6 output cols (Q0,Q1,K0,K1,V0,V1)
  float b1v[6];
  #pragma unroll
  for (int pp = 0; pp < 3; ++pp)
    #pragma unroll
    for (int jj = 0; jj < 2; ++jj)
      b1v[pp * 2 + jj] = b1[pp * DIM + h * 32 + jj * 16 + c];

  // ---- phase 1: QKV slice GEMM, one M-tile at a time (A full-K in regs)
  #pragma unroll
  for (int mt = 0; mt < 3; ++mt) {
    const int tile = w + 3 * mt;
    bf16x8 af[6];
    const float* rp = xg + (size_t)(tile * 16 + c) * DIM;
    #pragma unroll
    for (int ks = 0; ks < 6; ++ks) {
      const float4* fp = (const float4*)(rp + ks * 32 + q4 * 8);
      float4 f0 = fp[0], f1 = fp[1];
      u16x8 rr;
      rr[0] = f2b_bits(f0.x); rr[1] = f2b_bits(f0.y);
      rr[2] = f2b_bits(f0.z); rr[3] = f2b_bits(f0.w);
      rr[4] = f2b_bits(f1.x); rr[5] = f2b_bits(f1.y);
      rr[6] = f2b_bits(f1.z); rr[7] = f2b_bits(f1.w);
      af[ks] = __builtin_bit_cast(bf16x8, rr);
    }
    const f32x4 z = {0.f, 0.f, 0.f, 0.f};
    f32x4 acc[6];
    #pragma unroll
    for (int u = 0; u < 6; ++u) acc[u] = z;
    #pragma unroll
    for (int ks = 0; ks < 6; ++ks) {
      #pragma unroll
      for (int pp = 0; pp < 3; ++pp)
        #pragma unroll
        for (int jj = 0; jj < 2; ++jj) {
          bf16x8 bfr = ld_bf8(w1b + (size_t)(pp * DIM + h * 32 + jj * 16 + c) * DIM +
                              ks * 32 + q4 * 8);
          acc[pp * 2 + jj] = mfma16(af[ks], bfr, acc[pp * 2 + jj]);
        }
    }
    // epilogue: Q,K -> [n][d] LDS; V -> [dd][m] LDS (transposed)
    #pragma unroll
    for (int jj = 0; jj < 2; ++jj) {
      #pragma unroll
      for (int g = 0; g < 4; ++g) {
        const int row = tile * 16 + q4 * 4 + g;
        q_lds[row * 36 + jj * 16 + c] = f2b_bits(acc[0 * 2 + jj][g] + b1v[jj]);
        k_lds[row * 36 + jj * 16 + c] = f2b_bits(acc[1 * 2 + jj][g] + b1v[2 + jj]);
      }
      unsigned lo = (unsigned)f2b_bits(acc[4 + jj][0] + b1v[4 + jj]) |
                    ((unsigned)f2b_bits(acc[4 + jj][1] + b1v[4 + jj]) << 16);
      unsigned hi = (unsigned)f2b_bits(acc[4 + jj][2] + b1v[4 + jj]) |
                    ((unsigned)f2b_bits(acc[4 + jj][3] + b1v[4 + jj]) << 16);
      uint2 uu; uu.x = lo; uu.y = hi;
      *(uint2*)&vt[(jj * 16 + c) * 168 + tile * 16 + q4 * 4] = uu;
    }
  }
  __syncthreads();

  // ---- phase 2+3: attention rows for tiles {w, w+3, w+6}
  u16* wbuf = pch + w * (16 * 40);
  const f32x4 z = {0.f, 0.f, 0.f, 0.f};
  #pragma unroll 1
  for (int rti = 0; rti < 3; ++rti) {
    const int rt = w + 3 * rti;
    const int n0 = rt * 16 + q4 * 4;

    bf16x8 qa = ld_bf8(&q_lds[(rt * 16 + c) * 36 + q4 * 8]);
    f32x4 S[9];
    #pragma unroll
    for (int ct = 0; ct < 9; ++ct)
      S[ct] = mfma16(qa, ld_bf8(&k_lds[(ct * 16 + c) * 36 + q4 * 8]), z);

    #pragma unroll
    for (int ct = 0; ct < 9; ++ct) {
      const int m = ct * 16 + c;
      #pragma unroll
      for (int g = 0; g < 4; ++g) {
        const int n = n0 + g;
        S[ct][g] = S[ct][g] * SCALE + bias_g[pos[n * NTOK + m]] + mask_g[n * NTOK + m];
      }
    }
    float mx[4] = {-3e38f, -3e38f, -3e38f, -3e38f};
    #pragma unroll
    for (int ct = 0; ct < 9; ++ct)
      #pragma unroll
      for (int g = 0; g < 4; ++g) mx[g] = fmaxf(mx[g], S[ct][g]);
    #pragma unroll
    for (int g = 0; g < 4; ++g) {
      mx[g] = fmaxf(mx[g], __shfl_xor(mx[g], 1));
      mx[g] = fmaxf(mx[g], __shfl_xor(mx[g], 2));
      mx[g] = fmaxf(mx[g], __shfl_xor(mx[g], 4));
      mx[g] = fmaxf(mx[g], __shfl_xor(mx[g], 8));
    }
    float sm[4] = {0.f, 0.f, 0.f, 0.f};
    #pragma unroll
    for (int ct = 0; ct < 9; ++ct)
      #pragma unroll
      for (int g = 0; g < 4; ++g) {
        float e = __expf(S[ct][g] - mx[g]);
        S[ct][g] = e;
        sm[g] += e;
      }
    #pragma unroll
    for (int g = 0; g < 4; ++g) {
      sm[g] += __shfl_xor(sm[g], 1);
      sm[g] += __shfl_xor(sm[g], 2);
      sm[g] += __shfl_xor(sm[g], 4);
      sm[g] += __shfl_xor(sm[g], 8);
    }
    float inv[4];
    #pragma unroll
    for (int g = 0; g < 4; ++g) inv[g] = 1.0f / sm[g];

    f32x4 o0 = z, o1 = z;
    #pragma unroll
    for (int ks5 = 0; ks5 < 5; ++ks5) {
      #pragma unroll
      for (int cti = 0; cti < 2; ++cti) {
        const int ct = 2 * ks5 + cti;
        #pragma unroll
        for (int g = 0; g < 4; ++g) {
          u16 pv = 0;
          if (ct < 9) pv = f2b_bits(S[ct][g] * inv[g]);
          wbuf[(q4 * 4 + g) * 40 + cti * 16 + c] = pv;
        }
      }
      __asm__ volatile("" ::: "memory");  // keep LDS write->read program order
      bf16x8 pa = ld_bf8(&wbuf[c * 40 + q4 * 8]);
      o0 = mfma16(pa, ld_bf8(&vt[c * 168 + ks5 * 32 + q4 * 8]), o0);
      o1 = mfma16(pa, ld_bf8(&vt[(16 + c) * 168 + ks5 * 32 + q4 * 8]), o1);
      __asm__ volatile("" ::: "memory");
    }

    #pragma unroll
    for (int g = 0; g < 4; ++g) {
      Ow[((size_t)bw * NTOK + n0 + g) * DIM + h * 32 + c] = f2b_bits(o0[g]);
      Ow[((size_t)bw * NTOK + n0 + g) * DIM + h * 32 + 16 + c] = f2b_bits(o1[g]);
    }
  }
}

// ---------------------------------------------------------------------------
// K2: out = O @ w2^T + b2 ; LDS-free, per-(b,w) block, 576 threads = 9 waves
// ---------------------------------------------------------------------------
__global__ __launch_bounds__(576) void k_proj(const u16* __restrict__ Ow,
                                              const u16* __restrict__ w2b,
                                              const float* __restrict__ b2,
                                              float* __restrict__ out) {
  const int tid = threadIdx.x;
  const int w = tid >> 6;
  const int l = tid & 63;
  const int c = l & 15, q4 = l >> 4;
  const int bw = blockIdx.x;
  const int m3 = w % 3, ntg = w / 3;
  const size_t rbase = (size_t)bw * NTOK;

  const f32x4 z = {0.f, 0.f, 0.f, 0.f};
  f32x4 acc[3][4];
  #pragma unroll
  for (int i = 0; i < 3; ++i)
    #pragma unroll
    for (int j = 0; j < 4; ++j) acc[i][j] = z;

  #pragma unroll
  for (int ks = 0; ks < 6; ++ks) {
    bf16x8 af[3];
    #pragma unroll
    for (int i = 0; i < 3; ++i)
      af[i] = ld_bf8(Ow + (rbase + (m3 + 3 * i) * 16 + c) * DIM + ks * 32 + q4 * 8);
    bf16x8 bfg[4];
    #pragma unroll
    for (int j = 0; j < 4; ++j)
      bfg[j] = ld_bf8(w2b + (size_t)(ntg * 64 + j * 16 + c) * DIM + ks * 32 + q4 * 8);
    #pragma unroll
    for (int i = 0; i < 3; ++i)
      #pragma unroll
      for (int j = 0; j < 4; ++j) acc[i][j] = mfma16(af[i], bfg[j], acc[i][j]);
  }

  float b2v[4];
  #pragma unroll
  for (int j = 0; j < 4; ++j) b2v[j] = b2[ntg * 64 + j * 16 + c];

  #pragma unroll
  for (int i = 0; i < 3; ++i) {
    const int rowb = (m3 + 3 * i) * 16 + q4 * 4;
    #pragma unroll
    for (int j = 0; j < 4; ++j)
      #pragma unroll
      for (int g = 0; g < 4; ++g)
        out[(rbase + rowb + g) * DIM + ntg * 64 + j * 16 + c] = acc[i][j][g] + b2v[j];
  }
}

// ---------------------------------------------------------------------------
extern "C" void kernel_launch(void* const* d_in, const int* in_sizes, int n_in,
                              void* d_out, int out_size, void* d_ws, size_t ws_size,
                              hipStream_t stream) {
  const float* x = (const float*)d_in[0];
  const float* mask = (const float*)d_in[1];
  const float* w1 = (const float*)d_in[2];
  const float* b1 = (const float*)d_in[3];
  const float* w2 = (const float*)d_in[4];
  const float* b2 = (const float*)d_in[5];
  const float* bias_table = (const float*)d_in[6];
  const int* pos = (const int*)d_in[7];
  float* out = (float*)d_out;

  char* ws = (char*)d_ws;
  // ws layout (bytes):
  //   bias_t : 3312*840*6*4 = 66,769,920
  //   w1b    : 576*192*2    =    221,184   @ 66,769,920
  //   w2b    : 192*192*2    =     73,728   @ 66,991,104
  //   Ow     : 2*840*144*192*2 = 92,897,280 @ 67,064,832  (total ~160 MB)
  float* bias_t = (float*)ws;
  u16* w1b = (u16*)(ws + 66769920);
  u16* w2b = (u16*)(ws + 66991104);
  u16* Ow = (u16*)(ws + 67064832);

  k_prep<<<dim3(52 * 79 + 576), dim3(256), 0, stream>>>(bias_table, w1, w2,
                                                        bias_t, w1b, w2b);
  k_attn<<<dim3(2 * NW * HEADS), dim3(192), 0, stream>>>(x, mask, b1, w1b, bias_t,
                                                         pos, Ow);
  k_proj<<<dim3(2 * NW), dim3(576), 0, stream>>>(Ow, w2b, b2, out);
}